// Round 1
// baseline (12063.052 us; speedup 1.0000x reference)
//
#include <hip/hip_runtime.h>
#include <cstdint>
#include <cstddef>

#define SEQ   2048
#define BTOT  48
#define INDIM 128
#define HDIM  256
#define BG    16      // batches per group
#define NBG   3       // batch groups
#define USL   32      // hidden units per WG
#define NMEM  8       // WGs per cluster
#define NTHR  512

typedef short bf16x8 __attribute__((ext_vector_type(8)));
typedef float f32x4  __attribute__((ext_vector_type(4)));

__device__ __forceinline__ unsigned short f2bf(float f){
  union {float f; unsigned u;} v; v.f = f;
  unsigned r = v.u + 0x7fffu + ((v.u >> 16) & 1u);   // RNE
  return (unsigned short)(r >> 16);
}
__device__ __forceinline__ float bf2f(unsigned short h){
  union {unsigned u; float f;} v; v.u = ((unsigned)h) << 16; return v.f;
}
__device__ __forceinline__ float sigm(float xv){ return 1.0f/(1.0f + __expf(-xv)); }
__device__ __forceinline__ float tanh_(float xv){ return 1.0f - 2.0f/(__expf(2.0f*xv) + 1.0f); }

__device__ __forceinline__ void pollEq(const unsigned* f, unsigned want, int tid){
  const unsigned* p = f + (tid & (NMEM-1));
  // per-lane loop: SIMT exec-mask keeps the wave spinning until ALL 8 flags seen
  while (__hip_atomic_load(p, __ATOMIC_RELAXED, __HIP_MEMORY_SCOPE_AGENT) != want)
    __builtin_amdgcn_s_sleep(2);
  asm volatile("" ::: "memory");
}
__device__ __forceinline__ void pollGe(const unsigned* f, unsigned want, int tid){
  const unsigned* p = f + (tid & (NMEM-1));
  while (__hip_atomic_load(p, __ATOMIC_RELAXED, __HIP_MEMORY_SCOPE_AGENT) < want)
    __builtin_amdgcn_s_sleep(2);
  asm volatile("" ::: "memory");
}

// LAYER 0: gates = x[t]@Wih0^T + h0@Whh0^T + b   (K = 128 + 256)
// LAYER 1: gates = y0[t]@Wih1^T + h1@Whh1^T + b  (K = 256 + 256)
template<int LAYER>
__device__ __forceinline__ void run_layer(
    const float* __restrict__ x,
    const float* __restrict__ Wih, const float* __restrict__ Whh,
    const float* __restrict__ bih, const float* __restrict__ bhh,
    unsigned* __restrict__ h0buf, unsigned* __restrict__ h1buf,
    unsigned* __restrict__ flags0, unsigned* __restrict__ flags1,
    float* __restrict__ y1buf, float* __restrict__ hn_out,
    int bg, int m, int D,
    unsigned (*hstage)[524], float (*xstage)[132], float (*gacc)[132])
{
  const int Dm1  = D - 1;
  const int tid  = threadIdx.x;
  const int wave = tid >> 6;       // jtile 0..7
  const int lane = tid & 63;
  const int l15  = lane & 15;      // A row / B col / D col
  const int krow = lane >> 4;      // 0..3
  const int u_base = m * USL;

  constexpr int KIH = LAYER ? 256 : 128;
  constexpr int NKI = KIH / 32;    // input k-tiles (8 or 4)
  constexpr int NKT = NKI + 8;     // + 8 recurrent k-tiles

  // ---- persistent weights as MFMA B-fragments: lane holds W[jglob][k0..k0+7] ----
  const int jl    = wave*16 + l15;            // j-local 0..127 = gate*32 + ul
  const int gg    = jl >> 5;
  const int ul    = jl & 31;
  const int jglob = gg*HDIM + u_base + ul;
  bf16x8 wfrag[NKT];
  #pragma unroll
  for (int kt = 0; kt < NKT; ++kt){
    const float* src = (kt < NKI)
        ? (Wih + (size_t)jglob*KIH + kt*32 + krow*8)
        : (Whh + (size_t)jglob*HDIM + (kt-NKI)*32 + krow*8);
    bf16x8 h8;
    #pragma unroll
    for (int i = 0; i < 8; ++i) h8[i] = (short)f2bf(src[i]);
    wfrag[kt] = h8;
  }

  // ---- activation-thread mapping: tid -> (batch ab, unit au); c-state in reg ----
  const int ab = tid >> 5;
  const int au = tid & 31;
  const float bias0 = bih[0*HDIM + u_base + au] + bhh[0*HDIM + u_base + au];
  const float bias1 = bih[1*HDIM + u_base + au] + bhh[1*HDIM + u_base + au];
  const float bias2 = bih[2*HDIM + u_base + au] + bhh[2*HDIM + u_base + au];
  const float bias3 = bih[3*HDIM + u_base + au] + bhh[3*HDIM + u_base + au];
  float cst = 0.0f;

  const int sb  = tid >> 5;          // staging row (batch)
  const int su8 = (tid & 31) * 8;    // staging 8-word chunk

  for (int s = 0; s < SEQ; ++s){
    const int wslot = s & Dm1;
    f32x4 acc = {0.f, 0.f, 0.f, 0.f};

    if (LAYER == 0){
      // stage x[t] (off the critical path: before the h poll)
      {
        const float4 xv = *(const float4*)(x + ((size_t)s*BTOT + bg*BG + sb)*INDIM + (tid & 31)*4);
        *(float4*)&xstage[sb][(tid & 31)*4] = xv;
      }
      __syncthreads();
      #pragma unroll
      for (int kt = 0; kt < NKI; ++kt){
        const float* xr = &xstage[l15][kt*32 + krow*8];
        bf16x8 a;
        #pragma unroll
        for (int i = 0; i < 8; ++i) a[i] = (short)f2bf(xr[i]);
        acc = __builtin_amdgcn_mfma_f32_16x16x32_bf16(a, wfrag[kt], acc, 0, 0, 0);
      }
      if (s > 0)
        pollEq(flags0 + ((size_t)((s-1) & Dm1)*NBG + bg)*NMEM, (unsigned)s, tid);
      if (s >= D-2)   // ring-overwrite guard: L1 must have finished step s-(D-2)
        pollGe(flags1 + ((size_t)((s-(D-2)) & Dm1)*NBG + bg)*NMEM, (unsigned)(s-(D-2)+1), tid);
      if (s > 0){
        const unsigned* src = h0buf + (((size_t)((s-1) & Dm1)*NBG + bg)*BG + sb)*HDIM + su8;
        unsigned wv[8];
        #pragma unroll
        for (int i = 0; i < 8; ++i)
          wv[i] = __hip_atomic_load(src + i, __ATOMIC_RELAXED, __HIP_MEMORY_SCOPE_AGENT);
        #pragma unroll
        for (int i = 0; i < 8; ++i) hstage[sb][su8 + i] = wv[i];
      }
      __syncthreads();
      if (s > 0){
        #pragma unroll
        for (int kt = NKI; kt < NKT; ++kt){
          const unsigned* hr = &hstage[l15][(kt-NKI)*32 + krow*8];
          bf16x8 a;
          #pragma unroll
          for (int i = 0; i < 8; ++i) a[i] = (short)(hr[i] & 0xffffu);  // low16 = bf16 hi
          acc = __builtin_amdgcn_mfma_f32_16x16x32_bf16(a, wfrag[kt], acc, 0, 0, 0);
        }
      }
    } else {
      pollEq(flags0 + ((size_t)wslot*NBG + bg)*NMEM, (unsigned)(s+1), tid);           // y0[s]
      if (s > 0)
        pollEq(flags1 + ((size_t)((s-1) & Dm1)*NBG + bg)*NMEM, (unsigned)s, tid);     // h1[s-1]
      {
        const unsigned* src = h0buf + (((size_t)wslot*NBG + bg)*BG + sb)*HDIM + su8;
        unsigned wv[8];
        #pragma unroll
        for (int i = 0; i < 8; ++i)
          wv[i] = __hip_atomic_load(src + i, __ATOMIC_RELAXED, __HIP_MEMORY_SCOPE_AGENT);
        #pragma unroll
        for (int i = 0; i < 8; ++i) hstage[sb][su8 + i] = wv[i];        // cols 0..255 = y0
      }
      if (s > 0){
        const unsigned* src = h1buf + (((size_t)((s-1) & Dm1)*NBG + bg)*BG + sb)*HDIM + su8;
        unsigned wv[8];
        #pragma unroll
        for (int i = 0; i < 8; ++i)
          wv[i] = __hip_atomic_load(src + i, __ATOMIC_RELAXED, __HIP_MEMORY_SCOPE_AGENT);
        #pragma unroll
        for (int i = 0; i < 8; ++i) hstage[sb][256 + su8 + i] = wv[i];  // cols 256..511 = h1
      }
      __syncthreads();
      #pragma unroll
      for (int kt = 0; kt < NKI; ++kt){
        const unsigned* hr = &hstage[l15][kt*32 + krow*8];
        bf16x8 a;
        #pragma unroll
        for (int i = 0; i < 8; ++i) a[i] = (short)(hr[i] & 0xffffu);
        acc = __builtin_amdgcn_mfma_f32_16x16x32_bf16(a, wfrag[kt], acc, 0, 0, 0);
      }
      if (s > 0){
        #pragma unroll
        for (int kt = NKI; kt < NKT; ++kt){
          const unsigned* hr = &hstage[l15][kt*32 + krow*8];   // NKI==8 -> cols 256..
          bf16x8 a;
          #pragma unroll
          for (int i = 0; i < 8; ++i) a[i] = (short)(hr[i] & 0xffffu);
          acc = __builtin_amdgcn_mfma_f32_16x16x32_bf16(a, wfrag[kt], acc, 0, 0, 0);
        }
      }
    }

    // D layout: col = lane&15, row = krow*4 + r  -> gates[16b][128j]
    #pragma unroll
    for (int r = 0; r < 4; ++r) gacc[krow*4 + r][wave*16 + l15] = acc[r];
    __syncthreads();

    // ---- activations (all 512 threads = 16b x 32u) ----
    {
      const float pi = gacc[ab][0*32 + au] + bias0;
      const float pf = gacc[ab][1*32 + au] + bias1;
      const float pg = gacc[ab][2*32 + au] + bias2;
      const float po = gacc[ab][3*32 + au] + bias3;
      const float iv = sigm(pi), fv = sigm(pf), gv = tanh_(pg), ov = sigm(po);
      cst = fv*cst + iv*gv;
      const float hv = ov * tanh_(cst);
      const unsigned short hi = f2bf(hv);
      const unsigned short lo = f2bf(hv - bf2f(hi));
      const unsigned word = (unsigned)hi | ((unsigned)lo << 16);
      unsigned* dst = (LAYER ? h1buf : h0buf) + (((size_t)wslot*NBG + bg)*BG + ab)*HDIM + u_base + au;
      __hip_atomic_store(dst, word, __ATOMIC_RELAXED, __HIP_MEMORY_SCOPE_AGENT);
      if (LAYER == 1 && bg == 2 && ab == 15)
        y1buf[(size_t)s*HDIM + u_base + au] = hv;     // batch 47 row for the FC head
      if (s == SEQ-1)
        hn_out[(size_t)LAYER*BTOT*HDIM + (size_t)(bg*BG + ab)*HDIM + u_base + au] = hv;
    }
    asm volatile("s_waitcnt vmcnt(0)" ::: "memory");  // h words at coherence point
    __syncthreads();
    if (tid == 0){
      unsigned* fl = (LAYER ? flags1 : flags0) + ((size_t)wslot*NBG + bg)*NMEM + m;
      __hip_atomic_store(fl, (unsigned)(s+1), __ATOMIC_RELAXED, __HIP_MEMORY_SCOPE_AGENT);
    }
  }
}

__global__ __launch_bounds__(NTHR, 1)
void lstm_main(const float* __restrict__ x,
               const float* __restrict__ Wih0, const float* __restrict__ Whh0,
               const float* __restrict__ bih0, const float* __restrict__ bhh0,
               const float* __restrict__ Wih1, const float* __restrict__ Whh1,
               const float* __restrict__ bih1, const float* __restrict__ bhh1,
               unsigned* h0buf, unsigned* h1buf,
               unsigned* flags0, unsigned* flags1,
               float* y1buf, float* hn_out, int D)
{
  __shared__ unsigned hstage[16][524];   // padded vs bank conflicts
  __shared__ float    xstage[16][132];
  __shared__ float    gacc[16][132];

  const int c = blockIdx.x & 7;          // cluster: (layer, bgroup); 6,7 idle
  if (c >= 6) return;
  const int m  = blockIdx.x >> 3;        // member 0..7 (u-slice)
  const int bg = c >> 1;
  if ((c & 1) == 0)
    run_layer<0>(x, Wih0, Whh0, bih0, bhh0, h0buf, h1buf, flags0, flags1,
                 y1buf, hn_out, bg, m, D, hstage, xstage, gacc);
  else
    run_layer<1>(x, Wih1, Whh1, bih1, bhh1, h0buf, h1buf, flags0, flags1,
                 y1buf, hn_out, bg, m, D, hstage, xstage, gacc);
}

__global__ void lstm_out(const float* __restrict__ y1buf, const float* __restrict__ fcw,
                         const float* __restrict__ fcb, float* __restrict__ out)
{
  const int row  = blockIdx.x * 4 + (threadIdx.x >> 6);
  const int lane = threadIdx.x & 63;
  const float4 yv = *(const float4*)(y1buf + (size_t)row*HDIM + lane*4);
  const float4 wv = *(const float4*)(fcw + lane*4);
  float v = yv.x*wv.x + yv.y*wv.y + yv.z*wv.z + yv.w*wv.w;
  #pragma unroll
  for (int off = 32; off; off >>= 1) v += __shfl_down(v, off, 64);
  if (lane == 0) out[row] = v + fcb[0];
}

extern "C" void kernel_launch(void* const* d_in, const int* in_sizes, int n_in,
                              void* d_out, int out_size, void* d_ws, size_t ws_size,
                              hipStream_t stream)
{
  const float* x    = (const float*)d_in[0];
  const float* Wih0 = (const float*)d_in[1];
  const float* Whh0 = (const float*)d_in[2];
  const float* bih0 = (const float*)d_in[3];
  const float* bhh0 = (const float*)d_in[4];
  const float* Wih1 = (const float*)d_in[5];
  const float* Whh1 = (const float*)d_in[6];
  const float* bih1 = (const float*)d_in[7];
  const float* bhh1 = (const float*)d_in[8];
  const float* fcw  = (const float*)d_in[9];
  const float* fcb  = (const float*)d_in[10];
  float* out = (float*)d_out;            // [2048] out, then [2*48*256] hn

  const size_t y1bytes = (size_t)SEQ*HDIM*sizeof(float);
  int D = 2048;
  while (D > 4){
    size_t need = 2*((size_t)D*NBG*BG*HDIM*4) + 2*((size_t)D*NBG*NMEM*4) + y1bytes + 1024;
    if (need <= ws_size) break;
    D >>= 1;
  }
  char* p = (char*)d_ws;
  unsigned* h0buf  = (unsigned*)p; p += (size_t)D*NBG*BG*HDIM*4;
  unsigned* h1buf  = (unsigned*)p; p += (size_t)D*NBG*BG*HDIM*4;
  unsigned* flags0 = (unsigned*)p; p += (size_t)D*NBG*NMEM*4;
  unsigned* flags1 = (unsigned*)p; p += (size_t)D*NBG*NMEM*4;
  float*    y1buf  = (float*)p;

  // reset flags every call (graph replays re-run this memset node)
  hipMemsetAsync(flags0, 0, 2*(size_t)D*NBG*NMEM*4, stream);

  hipLaunchKernelGGL(lstm_main, dim3(64), dim3(NTHR), 0, stream,
                     x, Wih0, Whh0, bih0, bhh0, Wih1, Whh1, bih1, bhh1,
                     h0buf, h1buf, flags0, flags1, y1buf, out + SEQ, D);
  hipLaunchKernelGGL(lstm_out, dim3(SEQ/4), dim3(256), 0, stream,
                     y1buf, fcw, fcb, out);
}

// Round 2
// 5614.146 us; speedup vs baseline: 2.1487x; 2.1487x over previous
//
#include <hip/hip_runtime.h>
#include <cstdint>
#include <cstddef>

#define SEQ   2048
#define BTOT  48
#define INDIM 128
#define HDIM  256
#define BG    16      // batches per group
#define NBG   3       // batch groups
#define USL   32      // hidden units per WG
#define NMEM  8       // WGs per cluster
#define NTHR  512

typedef short    bf16x8 __attribute__((ext_vector_type(8)));
typedef float    f32x4  __attribute__((ext_vector_type(4)));
typedef unsigned u32x4  __attribute__((ext_vector_type(4)));

__device__ __forceinline__ unsigned short f2bf(float f){
  union {float f; unsigned u;} v; v.f = f;
  unsigned r = v.u + 0x7fffu + ((v.u >> 16) & 1u);   // RNE
  return (unsigned short)(r >> 16);
}
__device__ __forceinline__ float sigm(float xv){ return 1.0f/(1.0f + __expf(-xv)); }
__device__ __forceinline__ float tanh_(float xv){ return 1.0f - 2.0f/(__expf(2.0f*xv) + 1.0f); }

// coherent (bypass L1/L2, served at MALL) loads/stores for the h exchange
__device__ __forceinline__ void ld2x4_coh(const unsigned* p, u32x4& a, u32x4& b){
  asm volatile(
    "global_load_dwordx4 %0, %2, off sc0 sc1\n\t"
    "global_load_dwordx4 %1, %3, off sc0 sc1\n\t"
    "s_waitcnt vmcnt(0)"
    : "=v"(a), "=v"(b) : "v"(p), "v"(p+4) : "memory");
}
__device__ __forceinline__ void ld4x4_coh(const unsigned* p, const unsigned* q,
                                          u32x4& a, u32x4& b, u32x4& c, u32x4& d){
  asm volatile(
    "global_load_dwordx4 %0, %4, off sc0 sc1\n\t"
    "global_load_dwordx4 %1, %5, off sc0 sc1\n\t"
    "global_load_dwordx4 %2, %6, off sc0 sc1\n\t"
    "global_load_dwordx4 %3, %7, off sc0 sc1\n\t"
    "s_waitcnt vmcnt(0)"
    : "=v"(a), "=v"(b), "=v"(c), "=v"(d)
    : "v"(p), "v"(p+4), "v"(q), "v"(q+4) : "memory");
}
__device__ __forceinline__ void st_coh(unsigned* p, unsigned w){
  asm volatile("global_store_dword %0, %1, off sc0 sc1" :: "v"(p), "v"(w) : "memory");
}
__device__ __forceinline__ unsigned ld_coh(const unsigned* p){
  unsigned v;
  asm volatile("global_load_dword %0, %1, off sc0 sc1\n\ts_waitcnt vmcnt(0)"
               : "=v"(v) : "v"(p) : "memory");
  return v;
}
__device__ __forceinline__ int tags4(u32x4 a, unsigned want){
  return ((a[0]>>16)==want) & ((a[1]>>16)==want) & ((a[2]>>16)==want) & ((a[3]>>16)==want);
}
// 8 tagged dwords (bf16 in low half) -> 4 dwords of packed bf16 pairs
__device__ __forceinline__ u32x4 pack8(u32x4 a, u32x4 b){
  u32x4 r;
  r[0] = __builtin_amdgcn_perm(a[1], a[0], 0x05040100);
  r[1] = __builtin_amdgcn_perm(a[3], a[2], 0x05040100);
  r[2] = __builtin_amdgcn_perm(b[1], b[0], 0x05040100);
  r[3] = __builtin_amdgcn_perm(b[3], b[2], 0x05040100);
  return r;
}

// LAYER 0: gates = x[t]@Wih0^T + h0@Whh0^T + b   (K = 128 + 256)
// LAYER 1: gates = y0[t]@Wih1^T + h1@Whh1^T + b  (K = 256 + 256)
template<int LAYER>
__device__ __forceinline__ void run_layer(
    const float* __restrict__ x,
    const float* __restrict__ Wih, const float* __restrict__ Whh,
    const float* __restrict__ bih, const float* __restrict__ bhh,
    unsigned* __restrict__ h0buf, unsigned* __restrict__ h1buf,
    unsigned* __restrict__ flags,          // NBG*NMEM monotonic L1 progress counters
    float* __restrict__ y1buf, float* __restrict__ hn_out,
    int bg, int m, int D,
    char* __restrict__ smem_h, char* __restrict__ smem_x, float (*gacc)[132])
{
  const int Dm1  = D - 1;
  const int tid  = threadIdx.x;
  const int wave = tid >> 6;       // jtile 0..7
  const int lane = tid & 63;
  const int l15  = lane & 15;      // A row (batch) / D col
  const int krow = lane >> 4;      // 0..3
  const int u_base = m * USL;

  constexpr int KIH  = LAYER ? 256 : 128;
  constexpr int NKI  = KIH / 32;   // input k-tiles (8 or 4)
  constexpr int NKT  = NKI + 8;    // + 8 recurrent k-tiles
  constexpr int ROWB = LAYER ? 1024 : 512;   // smem_h bytes per batch row

  // ---- persistent weights as MFMA B-fragments ----
  const int jl    = wave*16 + l15;            // j-local = gate*32 + ul
  const int gg    = jl >> 5;
  const int ul    = jl & 31;
  const int jglob = gg*HDIM + u_base + ul;
  bf16x8 wfrag[NKT];
  #pragma unroll
  for (int kt = 0; kt < NKT; ++kt){
    const float* src = (kt < NKI)
        ? (Wih + (size_t)jglob*KIH + kt*32 + krow*8)
        : (Whh + (size_t)jglob*HDIM + (kt-NKI)*32 + krow*8);
    bf16x8 h8;
    #pragma unroll
    for (int i = 0; i < 8; ++i) h8[i] = (short)f2bf(src[i]);
    wfrag[kt] = h8;
  }

  // ---- activation mapping: tid -> (batch ab, unit au); c-state in reg ----
  const int ab = tid >> 5;
  const int au = tid & 31;
  const float bias0 = bih[0*HDIM + u_base + au] + bhh[0*HDIM + u_base + au];
  const float bias1 = bih[1*HDIM + u_base + au] + bhh[1*HDIM + u_base + au];
  const float bias2 = bih[2*HDIM + u_base + au] + bhh[2*HDIM + u_base + au];
  const float bias3 = bih[3*HDIM + u_base + au] + bhh[3*HDIM + u_base + au];
  float cst = 0.0f;

  const int sb  = tid >> 5;          // staging row (batch)
  const int i32 = tid & 31;          // 8-dword chunk id
  unsigned* prog = flags + bg*NMEM;
  const int swr = (sb & 7) << 4;     // write swizzle
  const int swl = (l15 & 7) << 4;    // read swizzle

  for (int s = 0; s < SEQ; ++s){
    const int wslot = s & Dm1;
    f32x4 acc = {0.f, 0.f, 0.f, 0.f};

    if (LAYER == 0){
      // ---- x stage + x MFMAs: independent of h, hidden under the wait ----
      {
        const float4 xv = *(const float4*)(x + ((size_t)s*BTOT + bg*BG + sb)*INDIM + i32*4);
        uint2 wv;
        wv.x = (unsigned)f2bf(xv.x) | ((unsigned)f2bf(xv.y) << 16);
        wv.y = (unsigned)f2bf(xv.z) | ((unsigned)f2bf(xv.w) << 16);
        *(uint2*)(smem_x + sb*256 + ((i32*8) ^ swr)) = wv;
      }
      __syncthreads();                               // B1: xstage ready
      #pragma unroll
      for (int kt = 0; kt < NKI; ++kt){
        bf16x8 af = *(const bf16x8*)(smem_x + l15*256 + ((kt*64 + krow*16) ^ swl));
        acc = __builtin_amdgcn_mfma_f32_16x16x32_bf16(af, wfrag[kt], acc, 0, 0, 0);
      }
      // ---- poll tagged h0[s-1] (tag == s) ----
      if (s > 0){
        const unsigned* ph = h0buf + (((size_t)((s-1) & Dm1)*NBG + bg)*BG + sb)*HDIM + i32*8;
        u32x4 a, b;
        do { ld2x4_coh(ph, a, b); } while (!(tags4(a, (unsigned)s) & tags4(b, (unsigned)s)));
        *(u32x4*)(smem_h + sb*ROWB + ((i32*16) ^ swr)) = pack8(a, b);
      }
      // ---- ring-overwrite guard, amortized 16x (almost never spins) ----
      if (((s & 15) == 0) && (s + 16 > D)){
        const unsigned want = (unsigned)(s + 16 - D);
        const unsigned* p = prog + (tid & 7);
        while (ld_coh(p) < want) __builtin_amdgcn_s_sleep(2);
      }
      __syncthreads();                               // B2: hstage ready
      if (s > 0){
        #pragma unroll
        for (int kt = 0; kt < 8; ++kt){
          bf16x8 af = *(const bf16x8*)(smem_h + l15*ROWB + ((kt*64 + krow*16) ^ swl));
          acc = __builtin_amdgcn_mfma_f32_16x16x32_bf16(af, wfrag[NKI+kt], acc, 0, 0, 0);
        }
      }
    } else {
      // ---- poll y0[s] (tag s+1) and h1[s-1] (tag s) together ----
      const unsigned* py = h0buf + (((size_t)wslot*NBG + bg)*BG + sb)*HDIM + i32*8;
      u32x4 a, b;
      if (s == 0){
        do { ld2x4_coh(py, a, b); } while (!(tags4(a, 1u) & tags4(b, 1u)));
      } else {
        const unsigned* ph = h1buf + (((size_t)((s-1) & Dm1)*NBG + bg)*BG + sb)*HDIM + i32*8;
        u32x4 c, d;
        do { ld4x4_coh(py, ph, a, b, c, d); }
        while (!(tags4(a, (unsigned)(s+1)) & tags4(b, (unsigned)(s+1))
               & tags4(c, (unsigned)s)     & tags4(d, (unsigned)s)));
        *(u32x4*)(smem_h + sb*ROWB + ((512 + i32*16) ^ swr)) = pack8(c, d);
      }
      *(u32x4*)(smem_h + sb*ROWB + ((i32*16) ^ swr)) = pack8(a, b);
      __syncthreads();                               // B2: hstage ready
      #pragma unroll
      for (int kt = 0; kt < NKI; ++kt){
        bf16x8 af = *(const bf16x8*)(smem_h + l15*ROWB + ((kt*64 + krow*16) ^ swl));
        acc = __builtin_amdgcn_mfma_f32_16x16x32_bf16(af, wfrag[kt], acc, 0, 0, 0);
      }
      if (s > 0){
        #pragma unroll
        for (int kt = NKI; kt < NKT; ++kt){
          bf16x8 af = *(const bf16x8*)(smem_h + l15*ROWB + ((kt*64 + krow*16) ^ swl));
          acc = __builtin_amdgcn_mfma_f32_16x16x32_bf16(af, wfrag[kt], acc, 0, 0, 0);
        }
      }
    }

    // D layout: col = lane&15 (j), row = krow*4 + r (batch) -> gacc[16b][128j]
    #pragma unroll
    for (int r = 0; r < 4; ++r) gacc[krow*4 + r][wave*16 + l15] = acc[r];
    __syncthreads();                                 // B3: gates ready

    // ---- activations (512 threads = 16 batches x 32 units) ----
    {
      const float pi = gacc[ab][0*32 + au] + bias0;
      const float pf = gacc[ab][1*32 + au] + bias1;
      const float pg = gacc[ab][2*32 + au] + bias2;
      const float po = gacc[ab][3*32 + au] + bias3;
      const float iv = sigm(pi), fv = sigm(pf), gv = tanh_(pg), ov = sigm(po);
      cst = fv*cst + iv*gv;
      const float hv = ov * tanh_(cst);
      const unsigned word = (unsigned)f2bf(hv) | ((unsigned)(s+1) << 16);
      unsigned* dst = (LAYER ? h1buf : h0buf)
                    + (((size_t)wslot*NBG + bg)*BG + ab)*HDIM + u_base + au;
      st_coh(dst, word);                             // fire-and-forget, self-validating
      if (LAYER == 1 && bg == 2 && ab == 15)
        y1buf[(size_t)s*HDIM + u_base + au] = hv;    // batch 47 row for the FC head
      if (s == SEQ-1)
        hn_out[(size_t)LAYER*BTOT*HDIM + (size_t)(bg*BG + ab)*HDIM + u_base + au] = hv;
    }
    if (LAYER == 1 && tid == 0)
      st_coh(prog + m, (unsigned)(s+1));             // monotonic progress (ring guard)
    // no trailing barrier needed: B1/B2 of next step provide the separation
  }
}

__global__ __launch_bounds__(NTHR, 1)
void lstm_main(const float* __restrict__ x,
               const float* __restrict__ Wih0, const float* __restrict__ Whh0,
               const float* __restrict__ bih0, const float* __restrict__ bhh0,
               const float* __restrict__ Wih1, const float* __restrict__ Whh1,
               const float* __restrict__ bih1, const float* __restrict__ bhh1,
               unsigned* h0buf, unsigned* h1buf, unsigned* flags,
               float* y1buf, float* hn_out, int D)
{
  __shared__ char  smem_h[16*1024];
  __shared__ char  smem_x[16*256];
  __shared__ float gacc[16][132];

  const int m  = blockIdx.x & 7;         // member: u-slice
  const int cl = blockIdx.x >> 3;        // 0..5
  const int bg = cl % 3;
  if (cl < 3)
    run_layer<0>(x, Wih0, Whh0, bih0, bhh0, h0buf, h1buf, flags,
                 y1buf, hn_out, bg, m, D, smem_h, smem_x, gacc);
  else
    run_layer<1>(x, Wih1, Whh1, bih1, bhh1, h0buf, h1buf, flags,
                 y1buf, hn_out, bg, m, D, smem_h, smem_x, gacc);
}

__global__ void lstm_out(const float* __restrict__ y1buf, const float* __restrict__ fcw,
                         const float* __restrict__ fcb, float* __restrict__ out)
{
  const int row  = blockIdx.x * 4 + (threadIdx.x >> 6);
  const int lane = threadIdx.x & 63;
  const float4 yv = *(const float4*)(y1buf + (size_t)row*HDIM + lane*4);
  const float4 wv = *(const float4*)(fcw + lane*4);
  float v = yv.x*wv.x + yv.y*wv.y + yv.z*wv.z + yv.w*wv.w;
  #pragma unroll
  for (int off = 32; off; off >>= 1) v += __shfl_down(v, off, 64);
  if (lane == 0) out[row] = v + fcb[0];
}

extern "C" void kernel_launch(void* const* d_in, const int* in_sizes, int n_in,
                              void* d_out, int out_size, void* d_ws, size_t ws_size,
                              hipStream_t stream)
{
  const float* x    = (const float*)d_in[0];
  const float* Wih0 = (const float*)d_in[1];
  const float* Whh0 = (const float*)d_in[2];
  const float* bih0 = (const float*)d_in[3];
  const float* bhh0 = (const float*)d_in[4];
  const float* Wih1 = (const float*)d_in[5];
  const float* Whh1 = (const float*)d_in[6];
  const float* bih1 = (const float*)d_in[7];
  const float* bhh1 = (const float*)d_in[8];
  const float* fcw  = (const float*)d_in[9];
  const float* fcb  = (const float*)d_in[10];
  float* out = (float*)d_out;            // [2048] out, then [2*48*256] hn

  int D = 64;                            // ring depth: 6.3 MB -> MALL-resident
  while (D > 8){
    size_t need = 2*((size_t)D*NBG*BG*HDIM*4) + 4096 + (size_t)SEQ*HDIM*sizeof(float);
    if (need <= ws_size) break;
    D >>= 1;
  }
  char* p = (char*)d_ws;
  unsigned* h0buf = (unsigned*)p; p += (size_t)D*NBG*BG*HDIM*4;
  unsigned* h1buf = (unsigned*)p; p += (size_t)D*NBG*BG*HDIM*4;
  unsigned* flags = (unsigned*)p; p += 4096;
  float*    y1buf = (float*)p;

  // zero all tags + progress counters every call (graph replays re-run this node)
  hipMemsetAsync(d_ws, 0, 2*(size_t)D*NBG*BG*HDIM*4 + 4096, stream);

  hipLaunchKernelGGL(lstm_main, dim3(48), dim3(NTHR), 0, stream,
                     x, Wih0, Whh0, bih0, bhh0, Wih1, Whh1, bih1, bhh1,
                     h0buf, h1buf, flags, y1buf, out + SEQ, D);
  hipLaunchKernelGGL(lstm_out, dim3(SEQ/4), dim3(256), 0, stream,
                     y1buf, fcw, fcb, out);
}